// Round 1
// baseline (2878.310 us; speedup 1.0000x reference)
//
#include <hip/hip_runtime.h>
#include <hip/hip_bf16.h>

// ---------------- problem constants ----------------
#define N_TOK 4096          // B*T = 2*2048
#define DIM   1024          // D
#define HID   4096          // H
#define NEXP  8             // E
#define NSLOT (N_TOK*2)     // N * TOP_K = 8192

// ---------------- GEMM tiling ----------------
#define BM 128
#define BN 128
#define BK 32
#define MAX_TILES (NSLOT/BM + NEXP)   // 64 + 8 = 72 worst case

// ws layout (bytes)
//   0    : counts[8], cursors[8], ntile(+pad), offs[9]   (ints, < 256B)
//   256  : desc[MAX_TILES] int4
//   2048 : topk_idx [NSLOT] int
//   +32K : topk_w   [NSLOT] float
//   +64K : slot_tok [NSLOT] int
//   +96K : slot_w   [NSLOT] float
//   133120 : h buffer [NSLOT][HID]  (float or bf16, by ws_size)
#define WS_DESC   256
#define WS_TIDX   2048
#define WS_TW     (2048 + 32768)
#define WS_STOK   (2048 + 2*32768)
#define WS_SW     (2048 + 3*32768)
#define WS_H      133120

__device__ __forceinline__ float gelu_exact(float v) {
    return 0.5f * v * (1.0f + erff(v * 0.70710678118654752f));
}

// ---- generic 8/16-element helpers (fp32 or bf16 storage of h) ----
__device__ __forceinline__ void load16f(float* d, const float* p) {
    float4 a = ((const float4*)p)[0], b = ((const float4*)p)[1];
    float4 c = ((const float4*)p)[2], e = ((const float4*)p)[3];
    d[0]=a.x; d[1]=a.y; d[2]=a.z; d[3]=a.w;  d[4]=b.x; d[5]=b.y; d[6]=b.z; d[7]=b.w;
    d[8]=c.x; d[9]=c.y; d[10]=c.z; d[11]=c.w; d[12]=e.x; d[13]=e.y; d[14]=e.z; d[15]=e.w;
}
__device__ __forceinline__ void load16f(float* d, const __hip_bfloat16* p) {
    union { uint4 q; __hip_bfloat16 b[8]; } t0, t1;
    t0.q = ((const uint4*)p)[0];
    t1.q = ((const uint4*)p)[1];
#pragma unroll
    for (int i = 0; i < 8; ++i) { d[i] = __bfloat162float(t0.b[i]); d[8+i] = __bfloat162float(t1.b[i]); }
}
__device__ __forceinline__ void store8f(float* p, const float* v) {
    ((float4*)p)[0] = make_float4(v[0],v[1],v[2],v[3]);
    ((float4*)p)[1] = make_float4(v[4],v[5],v[6],v[7]);
}
__device__ __forceinline__ void store8f(__hip_bfloat16* p, const float* v) {
    union { __hip_bfloat16 b[8]; uint4 q; } t;
#pragma unroll
    for (int i = 0; i < 8; ++i) t.b[i] = __float2bfloat16(v[i]);
    *(uint4*)p = t.q;
}

// ---------------- router: logits -> top2 -> renorm weights ----------------
__global__ __launch_bounds__(256) void moe_router(
    const float* __restrict__ x, const float* __restrict__ gw,
    int* __restrict__ topk_idx, float* __restrict__ topk_w,
    int* __restrict__ counts)
{
    __shared__ float gws[NEXP * DIM];           // [e][d] transposed
    int tid = threadIdx.x;
    for (int i = tid; i < NEXP * DIM; i += 256)
        gws[(i & 7) * DIM + (i >> 3)] = gw[i];  // gw is [d][e]
    __syncthreads();

    int wave = tid >> 6, lane = tid & 63;
    int tok = blockIdx.x * 4 + wave;
    const float* xr = x + (size_t)tok * DIM;

    float acc[NEXP];
#pragma unroll
    for (int e = 0; e < NEXP; ++e) acc[e] = 0.f;
#pragma unroll 4
    for (int it = 0; it < DIM / 64; ++it) {
        int d = it * 64 + lane;
        float xv = xr[d];
#pragma unroll
        for (int e = 0; e < NEXP; ++e) acc[e] = fmaf(xv, gws[e * DIM + d], acc[e]);
    }
#pragma unroll
    for (int e = 0; e < NEXP; ++e)
        for (int off = 32; off; off >>= 1) acc[e] += __shfl_down(acc[e], off);

    if (lane == 0) {
        int i0 = 0; float v0 = acc[0];
#pragma unroll
        for (int e = 1; e < NEXP; ++e) if (acc[e] > v0) { v0 = acc[e]; i0 = e; }
        int i1 = -1; float v1 = -3.4e38f;
#pragma unroll
        for (int e = 0; e < NEXP; ++e) if (e != i0 && acc[e] > v1) { v1 = acc[e]; i1 = e; }
        // renormalized top-2 softmax weights depend only on the two logits
        float w0 = 1.f / (1.f + expf(v1 - v0));
        topk_idx[tok * 2]     = i0;
        topk_idx[tok * 2 + 1] = i1;
        topk_w[tok * 2]       = w0;
        topk_w[tok * 2 + 1]   = 1.f - w0;
        atomicAdd(&counts[i0], 1);
        atomicAdd(&counts[i1], 1);
    }
}

// ---------------- prefix sum + tile descriptors ----------------
__global__ void moe_prefix(int* __restrict__ ctl, int4* __restrict__ desc)
{
    if (threadIdx.x != 0) return;
    int* counts  = ctl;
    int* cursors = ctl + 8;
    int* ntile   = ctl + 16;
    int* offs    = ctl + 24;
    int o = 0;
#pragma unroll
    for (int e = 0; e < NEXP; ++e) { offs[e] = o; cursors[e] = o; o += counts[e]; }
    offs[NEXP] = o;
    int t = 0;
    for (int e = 0; e < NEXP; ++e)
        for (int r0 = offs[e]; r0 < offs[e + 1]; r0 += BM) {
            int rows = offs[e + 1] - r0; if (rows > BM) rows = BM;
            desc[t++] = make_int4(e, r0, rows, 0);
        }
    *ntile = t;
}

// ---------------- scatter tokens into expert segments ----------------
__global__ __launch_bounds__(256) void moe_scatter(
    const int* __restrict__ topk_idx, const float* __restrict__ topk_w,
    int* __restrict__ cursors, int* __restrict__ slot_tok, float* __restrict__ slot_w)
{
    int g = blockIdx.x * 256 + threadIdx.x;
    if (g >= NSLOT) return;
    int e = topk_idx[g];
    int pos = atomicAdd(&cursors[e], 1);
    slot_tok[pos] = g >> 1;
    slot_w[pos]   = topk_w[g];
}

// ---------------- FFN1: h = gelu(X_gathered @ w1[e] + b1[e]) ----------------
template <typename HT>
__global__ __launch_bounds__(256) void moe_ffn1(
    const float* __restrict__ x, const float* __restrict__ w1, const float* __restrict__ b1,
    const int4* __restrict__ desc, const int* __restrict__ ntile,
    const int* __restrict__ slot_tok, HT* __restrict__ h)
{
    int tm = blockIdx.x;
    if (tm >= *ntile) return;
    int4 dd = desc[tm];
    int e = dd.x, row0 = dd.y, rows = dd.z;
    int n0 = blockIdx.y * BN;

    __shared__ float As[BK][BM + 4];
    __shared__ float Bs[BK][BN + 4];

    int tid = threadIdx.x;
    int am = tid & 127, akh = tid >> 7;                 // A: row am, k-half akh
    int tok = (am < rows) ? slot_tok[row0 + am] : -1;
    const float* aptr = x + (size_t)(tok < 0 ? 0 : tok) * DIM + akh * 16;
    int bk = tid >> 3, bn = (tid & 7) * 16;             // B: k row bk, 16 cols at bn
    const float* bptr = w1 + (size_t)e * DIM * HID + (size_t)bk * HID + n0 + bn;

    int tr = tid >> 4, tc = tid & 15;
    float c[8][8] = {};

    for (int k0 = 0; k0 < DIM; k0 += BK) {
        float av[16];
        if (tok >= 0) load16f(av, aptr + k0);
        else {
#pragma unroll
            for (int q = 0; q < 16; ++q) av[q] = 0.f;
        }
        float bv[16];
        load16f(bv, bptr + (size_t)k0 * HID);

        __syncthreads();
#pragma unroll
        for (int q = 0; q < 16; ++q) As[akh * 16 + q][am] = av[q];
#pragma unroll
        for (int q = 0; q < 4; ++q)
            *(float4*)&Bs[bk][bn + q * 4] = make_float4(bv[q*4], bv[q*4+1], bv[q*4+2], bv[q*4+3]);
        __syncthreads();

#pragma unroll
        for (int k = 0; k < BK; ++k) {
            float a[8], b[8];
            *(float4*)&a[0] = *(const float4*)&As[k][tr * 8];
            *(float4*)&a[4] = *(const float4*)&As[k][tr * 8 + 4];
            *(float4*)&b[0] = *(const float4*)&Bs[k][tc * 8];
            *(float4*)&b[4] = *(const float4*)&Bs[k][tc * 8 + 4];
#pragma unroll
            for (int i = 0; i < 8; ++i)
#pragma unroll
                for (int j = 0; j < 8; ++j) c[i][j] = fmaf(a[i], b[j], c[i][j]);
        }
    }

    const float* b1e = b1 + (size_t)e * HID + n0;
#pragma unroll
    for (int i = 0; i < 8; ++i) {
        int m = tr * 8 + i;
        if (m < rows) {
            HT* hp = h + (size_t)(row0 + m) * HID + n0 + tc * 8;
            float v[8];
#pragma unroll
            for (int j = 0; j < 8; ++j) v[j] = gelu_exact(c[i][j] + b1e[tc * 8 + j]);
            store8f(hp, v);
        }
    }
}

// ---------------- FFN2: out[tok] += w * (H_seg @ w2[e] + b2[e]) ----------------
template <typename HT>
__global__ __launch_bounds__(256) void moe_ffn2(
    const HT* __restrict__ h, const float* __restrict__ w2, const float* __restrict__ b2,
    const int4* __restrict__ desc, const int* __restrict__ ntile,
    const int* __restrict__ slot_tok, const float* __restrict__ slot_w,
    float* __restrict__ out)
{
    int tm = blockIdx.x;
    if (tm >= *ntile) return;
    int4 dd = desc[tm];
    int e = dd.x, row0 = dd.y, rows = dd.z;
    int n0 = blockIdx.y * BN;

    __shared__ float As[BK][BM + 4];
    __shared__ float Bs[BK][BN + 4];

    int tid = threadIdx.x;
    int am = tid & 127, akh = tid >> 7;
    bool aok = (am < rows);
    const HT* aptr = h + (size_t)(row0 + (aok ? am : 0)) * HID + akh * 16;
    int bk = tid >> 3, bn = (tid & 7) * 16;
    const float* bptr = w2 + (size_t)e * HID * DIM + (size_t)bk * DIM + n0 + bn;

    int tr = tid >> 4, tc = tid & 15;
    float c[8][8] = {};

    for (int k0 = 0; k0 < HID; k0 += BK) {
        float av[16];
        if (aok) load16f(av, aptr + k0);
        else {
#pragma unroll
            for (int q = 0; q < 16; ++q) av[q] = 0.f;
        }
        float bv[16];
        load16f(bv, bptr + (size_t)k0 * DIM);

        __syncthreads();
#pragma unroll
        for (int q = 0; q < 16; ++q) As[akh * 16 + q][am] = av[q];
#pragma unroll
        for (int q = 0; q < 4; ++q)
            *(float4*)&Bs[bk][bn + q * 4] = make_float4(bv[q*4], bv[q*4+1], bv[q*4+2], bv[q*4+3]);
        __syncthreads();

#pragma unroll
        for (int k = 0; k < BK; ++k) {
            float a[8], b[8];
            *(float4*)&a[0] = *(const float4*)&As[k][tr * 8];
            *(float4*)&a[4] = *(const float4*)&As[k][tr * 8 + 4];
            *(float4*)&b[0] = *(const float4*)&Bs[k][tc * 8];
            *(float4*)&b[4] = *(const float4*)&Bs[k][tc * 8 + 4];
#pragma unroll
            for (int i = 0; i < 8; ++i)
#pragma unroll
                for (int j = 0; j < 8; ++j) c[i][j] = fmaf(a[i], b[j], c[i][j]);
        }
    }

    const float* b2e = b2 + (size_t)e * DIM + n0;
#pragma unroll
    for (int i = 0; i < 8; ++i) {
        int m = tr * 8 + i;
        if (m < rows) {
            int slot = row0 + m;
            int t2   = slot_tok[slot];
            float sw = slot_w[slot];
            float* op = out + (size_t)t2 * DIM + n0 + tc * 8;
#pragma unroll
            for (int j = 0; j < 8; ++j)
                atomicAdd(&op[j], sw * (c[i][j] + b2e[tc * 8 + j]));
        }
    }
}

// ---------------- launch ----------------
extern "C" void kernel_launch(void* const* d_in, const int* in_sizes, int n_in,
                              void* d_out, int out_size, void* d_ws, size_t ws_size,
                              hipStream_t stream)
{
    const float* x   = (const float*)d_in[0];
    const float* gw  = (const float*)d_in[1];
    const float* w1  = (const float*)d_in[2];
    const float* b1  = (const float*)d_in[3];
    const float* w2  = (const float*)d_in[4];
    const float* b2  = (const float*)d_in[5];
    float* out = (float*)d_out;

    char* ws = (char*)d_ws;
    int*   ctl      = (int*)ws;                 // counts/cursors/ntile/offs
    int4*  desc     = (int4*)(ws + WS_DESC);
    int*   topk_idx = (int*)(ws + WS_TIDX);
    float* topk_w   = (float*)(ws + WS_TW);
    int*   slot_tok = (int*)(ws + WS_STOK);
    float* slot_w   = (float*)(ws + WS_SW);
    void*  hbuf     = (void*)(ws + WS_H);

    hipMemsetAsync(ctl, 0, 32, stream);  // counts only
    hipMemsetAsync(d_out, 0, (size_t)N_TOK * DIM * sizeof(float), stream);

    moe_router<<<N_TOK / 4, 256, 0, stream>>>(x, gw, topk_idx, topk_w, ctl);
    moe_prefix<<<1, 64, 0, stream>>>(ctl, desc);
    moe_scatter<<<NSLOT / 256, 256, 0, stream>>>(topk_idx, topk_w, ctl + 8, slot_tok, slot_w);

    dim3 blk(256);
    dim3 g1(MAX_TILES, HID / BN);
    dim3 g2(MAX_TILES, DIM / BN);
    size_t need_f32 = (size_t)WS_H + (size_t)NSLOT * HID * sizeof(float);

    if (ws_size >= need_f32) {
        float* h = (float*)hbuf;
        moe_ffn1<float><<<g1, blk, 0, stream>>>(x, w1, b1, desc, ctl + 16, slot_tok, h);
        moe_ffn2<float><<<g2, blk, 0, stream>>>(h, w2, b2, desc, ctl + 16, slot_tok, slot_w, out);
    } else {
        __hip_bfloat16* h = (__hip_bfloat16*)hbuf;
        moe_ffn1<__hip_bfloat16><<<g1, blk, 0, stream>>>(x, w1, b1, desc, ctl + 16, slot_tok, h);
        moe_ffn2<__hip_bfloat16><<<g2, blk, 0, stream>>>(h, w2, b2, desc, ctl + 16, slot_tok, slot_w, out);
    }
}

// Round 2
// 790.155 us; speedup vs baseline: 3.6427x; 3.6427x over previous
//
#include <hip/hip_runtime.h>
#include <hip/hip_bf16.h>

// ---------------- problem constants ----------------
#define N_TOK 4096          // B*T
#define DIM   1024          // D
#define HID   4096          // H
#define NEXP  8             // E
#define NSLOT (N_TOK*2)     // N * TOP_K

#define MAX_T1 (NSLOT/128 + NEXP)   // 72
#define MAX_T2 (NSLOT/64  + NEXP)   // 136

typedef __attribute__((ext_vector_type(8))) short bf16x8;
typedef __attribute__((ext_vector_type(4))) float f32x4;

// ---------------- ws layout (bytes) ----------------
#define WS_CTL    0            // counts[8]@0, cursors[8]@32, ntile1@64, ntile2@68, offs[9]@96
#define WS_DESC1  512
#define WS_DESC2  2048
#define WS_STOK   8192
#define WS_SW     40960
#define WS_TIDX   73728
#define WS_TW     106496
#define WS_XB     262144
#define WS_H      (WS_XB + (size_t)N_TOK*DIM*2)   // 8,650,752
#define WS_WT     (WS_H + (size_t)NSLOT*HID*2)    // 75,759,616
#define PER_E_B   ((size_t)DIM*HID*2)             // 8,388,608 per expert

__device__ __forceinline__ float gelu_exact(float v) {
    return 0.5f * v * (1.0f + erff(v * 0.70710678118654752f));
}

// async global->LDS, 16B per lane; lds dest must be wave-uniform base (+lane*16 in HW)
__device__ __forceinline__ void async16(const void* g, void* l) {
    __builtin_amdgcn_global_load_lds(
        (const __attribute__((address_space(1))) void*)g,
        (__attribute__((address_space(3))) void*)l, 16, 0, 0);
}

// ---------------- router: logits -> top2 -> renorm ----------------
__global__ __launch_bounds__(256) void moe_router(
    const float* __restrict__ x, const float* __restrict__ gw,
    int* __restrict__ topk_idx, float* __restrict__ topk_w,
    int* __restrict__ counts)
{
    __shared__ float gws[NEXP * DIM];
    int tid = threadIdx.x;
    for (int i = tid; i < NEXP * DIM; i += 256)
        gws[(i & 7) * DIM + (i >> 3)] = gw[i];      // gw is [d][e]
    __syncthreads();

    int wave = tid >> 6, lane = tid & 63;
    int tok = blockIdx.x * 4 + wave;
    const float* xr = x + (size_t)tok * DIM;

    float acc[NEXP];
#pragma unroll
    for (int e = 0; e < NEXP; ++e) acc[e] = 0.f;
#pragma unroll 4
    for (int it = 0; it < DIM / 64; ++it) {
        int d = it * 64 + lane;
        float xv = xr[d];
#pragma unroll
        for (int e = 0; e < NEXP; ++e) acc[e] = fmaf(xv, gws[e * DIM + d], acc[e]);
    }
#pragma unroll
    for (int e = 0; e < NEXP; ++e)
        for (int off = 32; off; off >>= 1) acc[e] += __shfl_down(acc[e], off);

    if (lane == 0) {
        int i0 = 0; float v0 = acc[0];
#pragma unroll
        for (int e = 1; e < NEXP; ++e) if (acc[e] > v0) { v0 = acc[e]; i0 = e; }
        int i1 = -1; float v1 = -3.4e38f;
#pragma unroll
        for (int e = 0; e < NEXP; ++e) if (e != i0 && acc[e] > v1) { v1 = acc[e]; i1 = e; }
        float w0 = 1.f / (1.f + expf(v1 - v0));
        topk_idx[tok * 2]     = i0;
        topk_idx[tok * 2 + 1] = i1;
        topk_w[tok * 2]       = w0;
        topk_w[tok * 2 + 1]   = 1.f - w0;
        atomicAdd(&counts[i0], 1);
        atomicAdd(&counts[i1], 1);
    }
}

// ---------------- prefix + tile descriptors (BM=128 and BM=64) ----------------
__global__ void moe_prefix(int* __restrict__ ctl, int4* __restrict__ desc1, int4* __restrict__ desc2)
{
    if (threadIdx.x != 0) return;
    int* counts = ctl; int* cursors = ctl + 8; int* offs = ctl + 24;
    int o = 0;
#pragma unroll
    for (int e = 0; e < NEXP; ++e) { offs[e] = o; cursors[e] = o; o += counts[e]; }
    offs[NEXP] = o;
    int t1 = 0, t2 = 0;
    for (int e = 0; e < NEXP; ++e) {
        for (int r0 = offs[e]; r0 < offs[e + 1]; r0 += 128) {
            int rows = offs[e + 1] - r0; if (rows > 128) rows = 128;
            desc1[t1++] = make_int4(e, r0, rows, 0);
        }
        for (int r0 = offs[e]; r0 < offs[e + 1]; r0 += 64) {
            int rows = offs[e + 1] - r0; if (rows > 64) rows = 64;
            desc2[t2++] = make_int4(e, r0, rows, 0);
        }
    }
    ctl[16] = t1; ctl[17] = t2;
}

// ---------------- scatter ----------------
__global__ __launch_bounds__(256) void moe_scatter(
    const int* __restrict__ topk_idx, const float* __restrict__ topk_w,
    int* __restrict__ cursors, int* __restrict__ slot_tok, float* __restrict__ slot_w)
{
    int g = blockIdx.x * 256 + threadIdx.x;
    if (g >= NSLOT) return;
    int e = topk_idx[g];
    int pos = atomicAdd(&cursors[e], 1);
    slot_tok[pos] = g >> 1;
    slot_w[pos]   = topk_w[g];
}

// ---------------- x fp32 -> bf16 ----------------
__global__ __launch_bounds__(256) void cvt_bf16_k(const float* __restrict__ in, __hip_bfloat16* __restrict__ outp)
{
    int i = (blockIdx.x * 256 + threadIdx.x) * 8;
    float4 a = *(const float4*)(in + i);
    float4 b = *(const float4*)(in + i + 4);
    union { __hip_bfloat16 h[8]; uint4 q; } u;
    u.h[0] = __float2bfloat16(a.x); u.h[1] = __float2bfloat16(a.y);
    u.h[2] = __float2bfloat16(a.z); u.h[3] = __float2bfloat16(a.w);
    u.h[4] = __float2bfloat16(b.x); u.h[5] = __float2bfloat16(b.y);
    u.h[6] = __float2bfloat16(b.z); u.h[7] = __float2bfloat16(b.w);
    *(uint4*)(outp + i) = u.q;
}

// ---------------- transpose+convert: in fp32 [z][R][C] -> out bf16 [z][C][R] ----------------
__global__ __launch_bounds__(256) void transpose_cvt(
    const float* __restrict__ in, __hip_bfloat16* __restrict__ outp, int R, int C)
{
    __shared__ float tile[64][65];
    size_t eoff = (size_t)blockIdx.z * R * C;
    const float* src = in + eoff;
    __hip_bfloat16* dst = outp + eoff;
    int c0 = blockIdx.x * 64, r0 = blockIdx.y * 64;
    int t = threadIdx.x;
    int lr = t >> 2, lc = (t & 3) << 4;
#pragma unroll
    for (int j = 0; j < 4; ++j) {
        float4 v = *(const float4*)(src + (size_t)(r0 + lr) * C + c0 + lc + j * 4);
        tile[lr][lc + j * 4 + 0] = v.x;
        tile[lr][lc + j * 4 + 1] = v.y;
        tile[lr][lc + j * 4 + 2] = v.z;
        tile[lr][lc + j * 4 + 3] = v.w;
    }
    __syncthreads();
    int oc = t >> 2, orr = (t & 3) << 4;
    union { __hip_bfloat16 hh[16]; uint4 q[2]; } u;
#pragma unroll
    for (int j = 0; j < 16; ++j)
        u.hh[j] = __float2bfloat16(tile[orr + j][oc]);
    __hip_bfloat16* dp = dst + (size_t)(c0 + oc) * R + r0 + orr;
    *(uint4*)(dp)     = u.q[0];
    *(uint4*)(dp + 8) = u.q[1];
}

// ============ FFN1: h = gelu(X_gather @ w1[e] + b1[e]),  128x128x64 MFMA ============
// A tile As[128 rows][64 k] bf16 (XOR-swizzled data, linear lds dest via pre-swizzled src)
// B tile Bs[128 n][64 k] from w1t [E][H][D]
__global__ __launch_bounds__(256, 2) void moe_ffn1(
    const __hip_bfloat16* __restrict__ xb, const __hip_bfloat16* __restrict__ wt,
    const float* __restrict__ b1, const int4* __restrict__ desc, const int* __restrict__ ctl,
    const int* __restrict__ slot_tok, __hip_bfloat16* __restrict__ h, int e0, int e1)
{
    __shared__ __hip_bfloat16 As[128 * 64];
    __shared__ __hip_bfloat16 Bs[128 * 64];

    int tm = blockIdx.x;
    if (tm >= ctl[16]) return;
    int4 dd = desc[tm];
    int e = dd.x;
    if (e < e0 || e >= e1) return;
    int row0 = dd.y, rows = dd.z;
    int n0 = blockIdx.y * 128;

    int tid = threadIdx.x;
    int sr  = tid >> 3;            // staging row base (0..31)
    int scb = (tid & 7) << 4;      // physical col byte

    const __hip_bfloat16* asrc[4];
    const __hip_bfloat16* bsrc[4];
#pragma unroll
    for (int i = 0; i < 4; ++i) {
        int r = sr + i * 32;
        int cbl = scb ^ ((r & 7) << 4);           // pre-swizzled source column
        int rr = row0 + r; if (rr > NSLOT - 1) rr = NSLOT - 1;
        asrc[i] = xb + (size_t)slot_tok[rr] * DIM + (cbl >> 1);
        bsrc[i] = wt + ((size_t)(e - e0) * HID + n0 + r) * DIM + (cbl >> 1);
    }

    int wid = tid >> 6, lane = tid & 63;
    int wr = wid >> 1, wc = wid & 1;
    int fr = lane & 15, fq = lane >> 4;
    int sw = (fr & 7) << 4;

    f32x4 acc[4][4] = {};

    char* abase = (char*)As + (wid << 10);
    char* bbase = (char*)Bs + (wid << 10);

    for (int k0 = 0; k0 < DIM; k0 += 64) {
        __syncthreads();
#pragma unroll
        for (int i = 0; i < 4; ++i) {
            async16(asrc[i] + k0, abase + (i << 12));
            async16(bsrc[i] + k0, bbase + (i << 12));
        }
        __syncthreads();
#pragma unroll
        for (int ks = 0; ks < 2; ++ks) {
            bf16x8 af[4], bfv[4];
            int cb = ((ks << 6) | (fq << 4)) ^ sw;
#pragma unroll
            for (int m = 0; m < 4; ++m)
                af[m] = *(const bf16x8*)((const char*)As + ((wr * 64 + m * 16 + fr) << 7) + cb);
#pragma unroll
            for (int n = 0; n < 4; ++n)
                bfv[n] = *(const bf16x8*)((const char*)Bs + ((wc * 64 + n * 16 + fr) << 7) + cb);
#pragma unroll
            for (int m = 0; m < 4; ++m)
#pragma unroll
                for (int n = 0; n < 4; ++n)
                    acc[m][n] = __builtin_amdgcn_mfma_f32_16x16x32_bf16(af[m], bfv[n], acc[m][n], 0, 0, 0);
        }
    }

    const float* b1p = b1 + (size_t)e * HID + n0;
#pragma unroll
    for (int m = 0; m < 4; ++m) {
#pragma unroll
        for (int rg = 0; rg < 4; ++rg) {
            int r = wr * 64 + m * 16 + fq * 4 + rg;
            if (r < rows) {
                __hip_bfloat16* hp = h + (size_t)(row0 + r) * HID + n0;
#pragma unroll
                for (int n = 0; n < 4; ++n) {
                    int c = wc * 64 + n * 16 + fr;
                    hp[c] = __float2bfloat16(gelu_exact(acc[m][n][rg] + b1p[c]));
                }
            }
        }
    }
}

// ============ FFN2: out[tok] += w * (H_seg @ w2[e] + b2[e]),  64x128x64 MFMA ============
__global__ __launch_bounds__(256, 2) void moe_ffn2(
    const __hip_bfloat16* __restrict__ h, const __hip_bfloat16* __restrict__ wt,
    const float* __restrict__ b2, const int4* __restrict__ desc2, const int* __restrict__ ctl,
    const int* __restrict__ slot_tok, const float* __restrict__ slot_w,
    float* __restrict__ out, int e0, int e1)
{
    __shared__ __hip_bfloat16 As[64 * 64];
    __shared__ __hip_bfloat16 Bs[128 * 64];

    int tm = blockIdx.x;
    if (tm >= ctl[17]) return;
    int4 dd = desc2[tm];
    int e = dd.x;
    if (e < e0 || e >= e1) return;
    int row0 = dd.y, rows = dd.z;
    int n0 = blockIdx.y * 128;

    int tid = threadIdx.x;
    int sr  = tid >> 3;
    int scb = (tid & 7) << 4;

    const __hip_bfloat16* asrc[2];
    const __hip_bfloat16* bsrc[4];
#pragma unroll
    for (int i = 0; i < 2; ++i) {
        int r = sr + i * 32;
        int cbl = scb ^ ((r & 7) << 4);
        int rr = row0 + r; if (rr > NSLOT - 1) rr = NSLOT - 1;
        asrc[i] = h + (size_t)rr * HID + (cbl >> 1);
    }
#pragma unroll
    for (int i = 0; i < 4; ++i) {
        int r = sr + i * 32;
        int cbl = scb ^ ((r & 7) << 4);
        bsrc[i] = wt + ((size_t)(e - e0) * DIM + n0 + r) * HID + (cbl >> 1);
    }

    int wid = tid >> 6, lane = tid & 63;
    int wr = wid >> 1, wc = wid & 1;
    int fr = lane & 15, fq = lane >> 4;
    int sw = (fr & 7) << 4;

    f32x4 acc[2][4] = {};

    char* abase = (char*)As + (wid << 10);
    char* bbase = (char*)Bs + (wid << 10);

    for (int k0 = 0; k0 < HID; k0 += 64) {
        __syncthreads();
#pragma unroll
        for (int i = 0; i < 2; ++i)
            async16(asrc[i] + k0, abase + (i << 12));
#pragma unroll
        for (int i = 0; i < 4; ++i)
            async16(bsrc[i] + k0, bbase + (i << 12));
        __syncthreads();
#pragma unroll
        for (int ks = 0; ks < 2; ++ks) {
            bf16x8 af[2], bfv[4];
            int cb = ((ks << 6) | (fq << 4)) ^ sw;
#pragma unroll
            for (int m = 0; m < 2; ++m)
                af[m] = *(const bf16x8*)((const char*)As + ((wr * 32 + m * 16 + fr) << 7) + cb);
#pragma unroll
            for (int n = 0; n < 4; ++n)
                bfv[n] = *(const bf16x8*)((const char*)Bs + ((wc * 64 + n * 16 + fr) << 7) + cb);
#pragma unroll
            for (int m = 0; m < 2; ++m)
#pragma unroll
                for (int n = 0; n < 4; ++n)
                    acc[m][n] = __builtin_amdgcn_mfma_f32_16x16x32_bf16(af[m], bfv[n], acc[m][n], 0, 0, 0);
        }
    }

    const float* b2p = b2 + (size_t)e * DIM + n0;
#pragma unroll
    for (int m = 0; m < 2; ++m) {
#pragma unroll
        for (int rg = 0; rg < 4; ++rg) {
            int r = wr * 32 + m * 16 + fq * 4 + rg;
            if (r < rows) {
                int slot = row0 + r;
                int tk = slot_tok[slot];
                float swt = slot_w[slot];
                float* op = out + (size_t)tk * DIM + n0;
#pragma unroll
                for (int n = 0; n < 4; ++n) {
                    int c = wc * 64 + n * 16 + fr;
                    atomicAdd(&op[c], swt * (acc[m][n][rg] + b2p[c]));
                }
            }
        }
    }
}

// ---------------- launch ----------------
extern "C" void kernel_launch(void* const* d_in, const int* in_sizes, int n_in,
                              void* d_out, int out_size, void* d_ws, size_t ws_size,
                              hipStream_t stream)
{
    const float* x   = (const float*)d_in[0];
    const float* gw  = (const float*)d_in[1];
    const float* w1  = (const float*)d_in[2];
    const float* b1  = (const float*)d_in[3];
    const float* w2  = (const float*)d_in[4];
    const float* b2  = (const float*)d_in[5];
    float* out = (float*)d_out;

    char* ws = (char*)d_ws;
    int*   ctl   = (int*)(ws + WS_CTL);
    int4*  desc1 = (int4*)(ws + WS_DESC1);
    int4*  desc2 = (int4*)(ws + WS_DESC2);
    int*   stok  = (int*)(ws + WS_STOK);
    float* swp   = (float*)(ws + WS_SW);
    int*   tidx  = (int*)(ws + WS_TIDX);
    float* tw    = (float*)(ws + WS_TW);
    __hip_bfloat16* xb = (__hip_bfloat16*)(ws + WS_XB);
    __hip_bfloat16* hb = (__hip_bfloat16*)(ws + WS_H);
    __hip_bfloat16* wt = (__hip_bfloat16*)(ws + WS_WT);

    // experts per weight-chunk, from available ws
    size_t avail = (ws_size > (size_t)WS_WT) ? ws_size - (size_t)WS_WT : PER_E_B;
    int NE = (int)(avail / PER_E_B);
    if (NE < 1) NE = 1;
    if (NE == 3) NE = 2;
    if (NE > 4) NE = 4;

    hipMemsetAsync(ctl, 0, 128, stream);
    hipMemsetAsync(out, 0, (size_t)N_TOK * DIM * sizeof(float), stream);

    cvt_bf16_k<<<(N_TOK * DIM) / 2048, 256, 0, stream>>>(x, xb);
    moe_router<<<N_TOK / 4, 256, 0, stream>>>(x, gw, tidx, tw, ctl);
    moe_prefix<<<1, 64, 0, stream>>>(ctl, desc1, desc2);
    moe_scatter<<<NSLOT / 256, 256, 0, stream>>>(tidx, tw, ctl + 8, stok, swp);

    for (int e0 = 0; e0 < NEXP; e0 += NE) {
        int ne = (NEXP - e0 < NE) ? NEXP - e0 : NE;
        dim3 tg(HID / 64, DIM / 64, ne);   // w1: R=DIM, C=HID
        transpose_cvt<<<tg, 256, 0, stream>>>(w1 + (size_t)e0 * DIM * HID, wt, DIM, HID);
        moe_ffn1<<<dim3(MAX_T1, HID / 128), 256, 0, stream>>>(xb, wt, b1, desc1, ctl, stok, hb, e0, e0 + ne);
    }
    for (int e0 = 0; e0 < NEXP; e0 += NE) {
        int ne = (NEXP - e0 < NE) ? NEXP - e0 : NE;
        dim3 tg(DIM / 64, HID / 64, ne);   // w2: R=HID, C=DIM
        transpose_cvt<<<tg, 256, 0, stream>>>(w2 + (size_t)e0 * HID * DIM, wt, HID, DIM);
        moe_ffn2<<<dim3(MAX_T2, DIM / 128), 256, 0, stream>>>(hb, wt, b2, desc2, ctl, stok, swp, out, e0, e0 + ne);
    }
}